// Round 10
// baseline (225.149 us; speedup 1.0000x reference)
//
#include <hip/hip_runtime.h>
#include <hip/hip_bf16.h>
#include <stdint.h>

typedef __attribute__((ext_vector_type(8)))  __bf16 bf16x8;
typedef __attribute__((ext_vector_type(16))) float  f32x16;

#define B_  2
#define H_  16
#define S_  2048
#define D_  128
#define BH_ (B_*H_)

__device__ __forceinline__ uint32_t f2bf1(float f){
  uint32_t u = __builtin_bit_cast(uint32_t, f);
  return (u + 0x7fffu + ((u >> 16) & 1u)) >> 16;
}
__device__ __forceinline__ uint32_t pk2(float a, float b){
  return f2bf1(a) | (f2bf1(b) << 16);
}
__device__ __forceinline__ float bf2f(unsigned short u){
  return __builtin_bit_cast(float, (uint32_t)u << 16);
}

// async global->LDS, 16B/lane, linear LDS dest
__device__ __forceinline__ void gld16(const void* g, void* l){
  __builtin_amdgcn_global_load_lds(
      (const __attribute__((address_space(1))) void*)g,
      (__attribute__((address_space(3))) void*)(uintptr_t)l, 16, 0, 0);
}

// Split unit table: code = qb*4 + c, LPT order (chunk length desc, tiles of 32 kv).
// nc(qb) = qb/4 + 1 (1,1,1,1,2,2,2,2,3,3,3,3,4,4,4,4).
__device__ const unsigned char TAB_S[40] = {
  60,61,62,63, 44,45,46, 28,29, 12,   // len 16
  56,57,58,59, 40,41,                 // len 15
  52,53,54,55, 42, 36, 24,25,         // len 14
  48,49,50,51, 37,38,                 // len 13
  32,33,34, 20,21, 8,                 // len 12
  16,17,                              // len 10
  4,                                  // len 8
  0                                   // len 4
};
// partial-slot prefix offsets for qb=4..15 (nc = 2,2,2,2,3,3,3,3,4,4,4,4)
__device__ const unsigned char OFFT[12] = {0,2,4,6,8,11,14,17,20,24,28,32};

// ---------- fused pre-pass: K->bf16 and V->Vt(bf16, transposed) ----------
__global__ void prep(const float* __restrict__ K, const float* __restrict__ V,
                     unsigned short* __restrict__ Kb, unsigned short* __restrict__ Vt){
  __shared__ __attribute__((aligned(16))) unsigned short t[64*68];
  const int kv0 = blockIdx.x * 64, d0 = blockIdx.y * 64, bh = blockIdx.z;
  const int tid = threadIdx.x;
  const float* Vp = V + (size_t)bh * S_ * D_;
  const float* Kp = K + (size_t)bh * S_ * D_;
  unsigned short* Ko = Kb + (size_t)bh * S_ * D_;
  for (int i = 0; i < 4; i++){
    int f = tid + i*256;
    int kv = f >> 4, c4 = f & 15;
    size_t idx = (size_t)(kv0+kv)*D_ + d0 + c4*4;
    float4 k = *(const float4*)(Kp + idx);
    *(uint2*)(Ko + idx) = make_uint2(pk2(k.x,k.y), pk2(k.z,k.w));
  }
  for (int i = 0; i < 4; i++){
    int f = tid + i*256;
    int kv = f >> 4, c4 = f & 15;
    float4 v = *(const float4*)(Vp + (size_t)(kv0+kv)*D_ + d0 + c4*4);
    *(uint2*)&t[kv*68 + c4*4] = make_uint2(pk2(v.x,v.y), pk2(v.z,v.w));
  }
  __syncthreads();
  unsigned short* Vo = Vt + (size_t)bh * D_ * S_;
  for (int i = 0; i < 4; i++){
    int g = tid + i*256;
    int d = g >> 4, c = g & 15, kv = c*4;
    ushort4 o;
    o.x = t[(kv+0)*68 + d];
    o.y = t[(kv+1)*68 + d];
    o.z = t[(kv+2)*68 + d];
    o.w = t[(kv+3)*68 + d];
    *(ushort4*)(Vo + (size_t)(d0+d)*S_ + kv0 + kv) = o;
  }
}

// ---------- flash-attention: KVBLK=32, 32x32 MFMA, in-register P, dbuf K/V ----------
// 4 waves x 32 q-rows = 128 q/block; 32KB LDS -> 4-5 blocks/CU.
__global__ __launch_bounds__(256, 4)
void attn_fwd(const float* __restrict__ Q, const unsigned short* __restrict__ Kb,
              const unsigned short* __restrict__ Vt, float* __restrict__ Out,
              unsigned short* __restrict__ Opart, float* __restrict__ MLpart,
              int splitFlag){
  __shared__ __attribute__((aligned(16))) unsigned short Klds[2][32*128]; // [kv][d] swz ^((kv&15)<<4)
  __shared__ __attribute__((aligned(16))) unsigned short Vlds[2][128*32]; // [d][kv] swz ^(((d>>1)&3)<<4)

  const int bi  = blockIdx.x;
  const int xcd = bi & 7;
  const int idx = bi >> 3;
  const int bh  = xcd + 8*(idx & 3);
  const int ui  = idx >> 2;
  int qb, c;
  if (splitFlag){ int e = TAB_S[ui]; qb = e >> 2; c = e & 3; }
  else { qb = 15 - ui; c = 0; }
  const int nc = splitFlag ? ((qb >> 2) + 1) : 1;
  const int nt = 4*qb + 4;
  int t0, tEnd;
  if (nc == 1){ t0 = 0; tEnd = nt; }
  else {
    int sz = nt/nc, rem = nt%nc;
    t0 = c*sz + (c < rem ? c : rem);
    tEnd = t0 + sz + (c < rem ? 1 : 0);
  }

  const int tid  = threadIdx.x;
  const int wave = tid >> 6, lane = tid & 63;
  const int q32  = lane & 31, hf = lane >> 5;
  const int wq0  = qb*128 + wave*32;
  const int dtw  = 4*qb + wave;     // wave's diagonal kv-tile (global index)
  const float qs = 0.08838834764831845f * 1.44269504088896f; // scale*log2(e)

  const char* Kg = (const char*)(Kb + (size_t)bh * S_ * D_);
  const char* Vg = (const char*)(Vt + (size_t)bh * D_ * S_);

  // staging source offsets (pre-swizzled; LDS dest linear p = wave*2048+i*1024+lane*16)
  uint32_t koff[2], voff[2];
  #pragma unroll
  for (int i = 0; i < 2; i++){
    int kr = wave*8 + i*4 + (lane >> 4);          // K row (256B rows)
    koff[i] = kr*256 + (((lane & 15) ^ (kr & 15)) << 4);
    int vr = wave*32 + i*16 + (lane >> 2);        // V row d (64B rows)
    voff[i] = vr*(S_*2) + (((lane & 3) ^ ((vr >> 1) & 3)) << 4);
  }

  auto stage = [&](int buf, int t){
    const char* kp = Kg + t*8192;    // 32 rows * 256 B
    const char* vp = Vg + t*64;      // 32 kv * 2 B
    char* kd = (char*)&Klds[buf][0] + wave*2048;
    char* vd = (char*)&Vlds[buf][0] + wave*2048;
    #pragma unroll
    for (int i = 0; i < 2; i++){
      gld16(kp + koff[i], kd + i*1024);
      gld16(vp + voff[i], vd + i*1024);
    }
  };

  // Q fragments, pre-scaled: lane holds Q[wq0+q32][ds*16 + hf*8 + j]
  uint4 qf[8];
  {
    const float* Qp = Q + ((size_t)bh * S_ + (wq0 + q32)) * D_ + hf*8;
    #pragma unroll
    for (int ds = 0; ds < 8; ds++){
      float4 a = *(const float4*)(Qp + ds*16);
      float4 b = *(const float4*)(Qp + ds*16 + 4);
      bf16x8 q8;
      q8[0] = (__bf16)(a.x*qs); q8[1] = (__bf16)(a.y*qs);
      q8[2] = (__bf16)(a.z*qs); q8[3] = (__bf16)(a.w*qs);
      q8[4] = (__bf16)(b.x*qs); q8[5] = (__bf16)(b.y*qs);
      q8[6] = (__bf16)(b.z*qs); q8[7] = (__bf16)(b.w*qs);
      qf[ds] = __builtin_bit_cast(uint4, q8);
    }
  }

  f32x16 o[4];
  #pragma unroll
  for (int db = 0; db < 4; db++) o[db] = (f32x16)(0.f);
  float m_run = -INFINITY, l_run = 0.f;

  stage(0, t0);
  __syncthreads();

  int cur = 0;
  for (int t = t0; t < tEnd; ++t){
    if (t + 1 < tEnd) stage(cur ^ 1, t + 1);   // prefetch; drains at end barrier

    if (t <= dtw){
      const bool diag = (t == dtw);
      const char* Kc = (const char*)&Klds[cur][0];
      const char* Vc = (const char*)&Vlds[cur][0];

      // ---- swapped QK^T: S^T = mfma(A=K, B=Q^T), 32x32x16
      f32x16 sa = (f32x16)(0.f);
      __builtin_amdgcn_s_setprio(1);
      #pragma unroll
      for (int ds = 0; ds < 8; ds++){
        int cb = (q32*256 + ds*32 + hf*16) ^ ((q32 & 15) << 4);
        bf16x8 kf = *(const bf16x8*)(Kc + cb);
        sa = __builtin_amdgcn_mfma_f32_32x32x16_bf16(
               kf, __builtin_bit_cast(bf16x8, qf[ds]), sa, 0, 0, 0);
      }
      __builtin_amdgcn_s_setprio(0);

      // ---- online softmax (log2 domain, defer-max); lane owns q-row q32;
      // its 16 regs cover kv = (r&3)+8*(r>>2)+4hf; partner lane^32 has the rest.
      float p[16];
      float pm = -INFINITY;
      const int q_abs = wq0 + q32;
      #pragma unroll
      for (int r = 0; r < 16; r++){
        float s = sa[r];
        if (diag){
          int kvl = t*32 + (r & 3) + 8*(r >> 2) + 4*hf;
          if (kvl > q_abs) s = -1e30f;
        }
        p[r] = s;
        pm = fmaxf(pm, s);
      }
      pm = fmaxf(pm, __shfl_xor(pm, 32));
      if (__any(pm > m_run + 11.5f)){
        float mn  = fmaxf(m_run, pm);
        float fac = exp2f(m_run - mn);
        float fv[16];
        #pragma unroll
        for (int r = 0; r < 16; r++) fv[r] = __shfl(fac, (r & 3) + 8*(r >> 2) + 4*hf);
        #pragma unroll
        for (int db = 0; db < 4; db++)
          #pragma unroll
          for (int r = 0; r < 16; r++) o[db][r] *= fv[r];
        l_run *= fac;
        m_run = mn;
      }
      float rs = 0.f;
      #pragma unroll
      for (int i = 0; i < 16; i++){ p[i] = exp2f(p[i] - m_run); rs += p[i]; }
      rs += __shfl_xor(rs, 32);
      l_run += rs;

      // ---- pack P to bf16 pairs: Wp[m][tt] = pk(kv = 8m+4hf+2tt, +1)
      uint32_t Wp[4][2];
      #pragma unroll
      for (int m = 0; m < 4; m++){
        #pragma unroll
        for (int tt = 0; tt < 2; tt++){
          float lo = p[4*m + 2*tt];
          float hi = p[4*m + 2*tt + 1];
          asm("v_cvt_pk_bf16_f32 %0, %1, %2" : "=v"(Wp[m][tt]) : "v"(lo), "v"(hi));
        }
      }

      // ---- PV: A = P (permlane32_swap redistribution), B = V from LDS
      __builtin_amdgcn_s_setprio(1);
      #pragma unroll
      for (int Ks = 0; Ks < 2; Ks++){
        uint32_t d0 = Wp[2*Ks][0], d2 = Wp[2*Ks + 1][0];
        asm volatile("v_permlane32_swap_b32 %0, %1" : "+v"(d0), "+v"(d2));
        uint32_t d1 = Wp[2*Ks][1], d3 = Wp[2*Ks + 1][1];
        asm volatile("v_permlane32_swap_b32 %0, %1" : "+v"(d1), "+v"(d3));
        uint4 pw = make_uint4(d0, d1, d2, d3);
        bf16x8 paf = __builtin_bit_cast(bf16x8, pw);
        #pragma unroll
        for (int db = 0; db < 4; db++){
          int row = db*32 + q32;
          int vb = (row*64 + Ks*32 + hf*16) ^ (((row >> 1) & 3) << 4);
          bf16x8 vf = *(const bf16x8*)(Vc + vb);
          o[db] = __builtin_amdgcn_mfma_f32_32x32x16_bf16(paf, vf, o[db], 0, 0, 0);
        }
      }
      __builtin_amdgcn_s_setprio(0);
    }

    __syncthreads();   // drains prefetch + publishes buf[cur^1]
    cur ^= 1;
  }

  // ---- epilogue
  if (nc == 1){
    float rl[16];
    #pragma unroll
    for (int r = 0; r < 16; r++)
      rl[r] = 1.f / __shfl(l_run, (r & 3) + 8*(r >> 2) + 4*hf);
    float* Op = Out + ((size_t)bh * S_ + wq0) * D_;
    #pragma unroll
    for (int db = 0; db < 4; db++){
      #pragma unroll
      for (int r = 0; r < 16; r++){
        int qrow = (r & 3) + 8*(r >> 2) + 4*hf;
        Op[(size_t)qrow*D_ + db*32 + q32] = o[db][r] * rl[r];
      }
    }
  } else {
    const int slot = bh*36 + OFFT[qb - 4] + c;
    unsigned short* Po = Opart + (size_t)slot * (128*128);
    float* Ml = MLpart + (size_t)slot * 256;
    #pragma unroll
    for (int db = 0; db < 4; db++){
      #pragma unroll
      for (int r = 0; r < 16; r++){
        int row = wave*32 + (r & 3) + 8*(r >> 2) + 4*hf;
        __bf16 bv = (__bf16)o[db][r];
        Po[row*128 + db*32 + q32] = __builtin_bit_cast(unsigned short, bv);
      }
    }
    if (hf == 0){
      Ml[(wave*32 + q32)*2 + 0] = m_run;
      Ml[(wave*32 + q32)*2 + 1] = l_run;
    }
  }
}

// ---------- combine kernel: merge the 2-4 kv-chunks of qb>=4 ----------
__global__ __launch_bounds__(256)
void combine(const unsigned short* __restrict__ Opart,
             const float* __restrict__ MLpart, float* __restrict__ Out){
  const int bx = blockIdx.x;            // 0..383 = bh*12 + (qb-4)
  const int bh = bx / 12, qi = bx % 12, qb = qi + 4;
  const int nc = (qb >> 2) + 1;
  const int base = bh*36 + OFFT[qi];
  const int row  = threadIdx.x >> 1;
  const int half = threadIdx.x & 1;

  float m[4] = {-INFINITY,-INFINITY,-INFINITY,-INFINITY};
  float l[4] = {0.f,0.f,0.f,0.f};
  float M = -INFINITY;
  #pragma unroll
  for (int c = 0; c < 4; c++) if (c < nc){
    m[c] = MLpart[(size_t)(base+c)*256 + row*2];
    l[c] = MLpart[(size_t)(base+c)*256 + row*2 + 1];
    M = fmaxf(M, m[c]);
  }
  float w[4] = {0.f,0.f,0.f,0.f};
  float den = 0.f;
  #pragma unroll
  for (int c = 0; c < 4; c++) if (c < nc){
    w[c] = exp2f(m[c] - M);
    den += l[c]*w[c];
  }
  float inv = 1.f / den;

  float* Or = Out + ((size_t)bh * S_ + qb*128 + row) * D_ + half*64;
  #pragma unroll
  for (int cc = 0; cc < 64; cc += 8){
    float acc[8] = {0,0,0,0,0,0,0,0};
    #pragma unroll
    for (int c = 0; c < 4; c++) if (c < nc){
      const unsigned short* Pr = Opart + (size_t)(base+c)*16384 + row*128 + half*64 + cc;
      ushort4 a0 = *(const ushort4*)(Pr), a1 = *(const ushort4*)(Pr + 4);
      acc[0] += bf2f(a0.x)*w[c]; acc[1] += bf2f(a0.y)*w[c];
      acc[2] += bf2f(a0.z)*w[c]; acc[3] += bf2f(a0.w)*w[c];
      acc[4] += bf2f(a1.x)*w[c]; acc[5] += bf2f(a1.y)*w[c];
      acc[6] += bf2f(a1.z)*w[c]; acc[7] += bf2f(a1.w)*w[c];
    }
    #pragma unroll
    for (int j = 0; j < 8; j++) Or[cc + j] = acc[j]*inv;
  }
}

extern "C" void kernel_launch(void* const* d_in, const int* in_sizes, int n_in,
                              void* d_out, int out_size, void* d_ws, size_t ws_size,
                              hipStream_t stream){
  const float* Q = (const float*)d_in[0];
  const float* K = (const float*)d_in[1];
  const float* V = (const float*)d_in[2];
  float* Out = (float*)d_out;

  unsigned short* Kb = (unsigned short*)d_ws;                  // 16.78 MB
  unsigned short* Vt = Kb + (size_t)BH_ * S_ * D_;             // 16.78 MB
  unsigned short* Opart = Vt + (size_t)BH_ * S_ * D_;          // 1152 x 32KB = 37.75 MB
  float* MLpart = (float*)(Opart + (size_t)1152 * 128 * 128);  // 1.18 MB

  const size_t need = (size_t)BH_*S_*D_*2*2
                    + (size_t)1152*128*128*2 + (size_t)1152*256*4;
  const int split = (ws_size >= need) ? 1 : 0;

  prep<<<dim3(S_/64, D_/64, BH_), 256, 0, stream>>>(K, V, Kb, Vt);
  attn_fwd<<<split ? 1280 : 512, 256, 0, stream>>>(Q, Kb, Vt, Out, Opart, MLpart, split);
  if (split) combine<<<384, 256, 0, stream>>>(Opart, MLpart, Out);
}

// Round 11
// 113.171 us; speedup vs baseline: 1.9895x; 1.9895x over previous
//
#include <hip/hip_runtime.h>
#include <hip/hip_bf16.h>
#include <stdint.h>

typedef __attribute__((ext_vector_type(8)))  __bf16 bf16x8;
typedef __attribute__((ext_vector_type(16))) float  f32x16;

#define B_  2
#define H_  16
#define S_  2048
#define D_  128
#define BH_ (B_*H_)

__device__ __forceinline__ uint32_t f2bf1(float f){
  uint32_t u = __builtin_bit_cast(uint32_t, f);
  return (u + 0x7fffu + ((u >> 16) & 1u)) >> 16;
}
__device__ __forceinline__ uint32_t pk2(float a, float b){
  return f2bf1(a) | (f2bf1(b) << 16);
}
__device__ __forceinline__ float bf2f(unsigned short u){
  return __builtin_bit_cast(float, (uint32_t)u << 16);
}

// async global->LDS, 16B/lane, linear LDS dest
__device__ __forceinline__ void gld16(const void* g, void* l){
  __builtin_amdgcn_global_load_lds(
      (const __attribute__((address_space(1))) void*)g,
      (__attribute__((address_space(3))) void*)(uintptr_t)l, 16, 0, 0);
}

// Split unit table: code = qb*4 + c, LPT order (chunk length desc, tiles of 32 kv).
// nc(qb) = qb/4 + 1 (1,1,1,1,2,2,2,2,3,3,3,3,4,4,4,4).
__device__ const unsigned char TAB_S[40] = {
  60,61,62,63, 44,45,46, 28,29, 12,   // len 16
  56,57,58,59, 40,41,                 // len 15
  52,53,54,55, 42, 36, 24,25,         // len 14
  48,49,50,51, 37,38,                 // len 13
  32,33,34, 20,21, 8,                 // len 12
  16,17,                              // len 10
  4,                                  // len 8
  0                                   // len 4
};
// partial-slot prefix offsets for qb=4..15 (nc = 2,2,2,2,3,3,3,3,4,4,4,4)
__device__ const unsigned char OFFT[12] = {0,2,4,6,8,11,14,17,20,24,28,32};

// ---------- fused pre-pass: K->bf16 and V->Vt(bf16, transposed) ----------
__global__ void prep(const float* __restrict__ K, const float* __restrict__ V,
                     unsigned short* __restrict__ Kb, unsigned short* __restrict__ Vt){
  __shared__ __attribute__((aligned(16))) unsigned short t[64*68];
  const int kv0 = blockIdx.x * 64, d0 = blockIdx.y * 64, bh = blockIdx.z;
  const int tid = threadIdx.x;
  const float* Vp = V + (size_t)bh * S_ * D_;
  const float* Kp = K + (size_t)bh * S_ * D_;
  unsigned short* Ko = Kb + (size_t)bh * S_ * D_;
  for (int i = 0; i < 4; i++){
    int f = tid + i*256;
    int kv = f >> 4, c4 = f & 15;
    size_t idx = (size_t)(kv0+kv)*D_ + d0 + c4*4;
    float4 k = *(const float4*)(Kp + idx);
    *(uint2*)(Ko + idx) = make_uint2(pk2(k.x,k.y), pk2(k.z,k.w));
  }
  for (int i = 0; i < 4; i++){
    int f = tid + i*256;
    int kv = f >> 4, c4 = f & 15;
    float4 v = *(const float4*)(Vp + (size_t)(kv0+kv)*D_ + d0 + c4*4);
    *(uint2*)&t[kv*68 + c4*4] = make_uint2(pk2(v.x,v.y), pk2(v.z,v.w));
  }
  __syncthreads();
  unsigned short* Vo = Vt + (size_t)bh * D_ * S_;
  for (int i = 0; i < 4; i++){
    int g = tid + i*256;
    int d = g >> 4, c = g & 15, kv = c*4;
    ushort4 o;
    o.x = t[(kv+0)*68 + d];
    o.y = t[(kv+1)*68 + d];
    o.z = t[(kv+2)*68 + d];
    o.w = t[(kv+3)*68 + d];
    *(ushort4*)(Vo + (size_t)(d0+d)*S_ + kv0 + kv) = o;
  }
}

// ---------- flash-attention: KVBLK=32, 32x32 MFMA, in-register P, dbuf K/V ----------
// 4 waves x 32 q-rows = 128 q/block; 32KB LDS; (256,3): VGPR cap 170 -> no spill,
// occupancy = min(LDS 5, VGPR ~3) = 3 blocks/CU.
__global__ __launch_bounds__(256, 3)
void attn_fwd(const float* __restrict__ Q, const unsigned short* __restrict__ Kb,
              const unsigned short* __restrict__ Vt, float* __restrict__ Out,
              unsigned short* __restrict__ Opart, float* __restrict__ MLpart,
              int splitFlag){
  __shared__ __attribute__((aligned(16))) unsigned short Klds[2][32*128]; // [kv][d] swz ^((kv&15)<<4)
  __shared__ __attribute__((aligned(16))) unsigned short Vlds[2][128*32]; // [d][kv] swz ^(((d>>1)&3)<<4)

  const int bi  = blockIdx.x;
  const int xcd = bi & 7;
  const int idx = bi >> 3;
  const int bh  = xcd + 8*(idx & 3);
  const int ui  = idx >> 2;
  int qb, c;
  if (splitFlag){ int e = TAB_S[ui]; qb = e >> 2; c = e & 3; }
  else { qb = 15 - ui; c = 0; }
  const int nc = splitFlag ? ((qb >> 2) + 1) : 1;
  const int nt = 4*qb + 4;
  int t0, tEnd;
  if (nc == 1){ t0 = 0; tEnd = nt; }
  else {
    int sz = nt/nc, rem = nt%nc;
    t0 = c*sz + (c < rem ? c : rem);
    tEnd = t0 + sz + (c < rem ? 1 : 0);
  }

  const int tid  = threadIdx.x;
  const int wave = tid >> 6, lane = tid & 63;
  const int q32  = lane & 31, hf = lane >> 5;
  const int wq0  = qb*128 + wave*32;
  const int dtw  = 4*qb + wave;     // wave's diagonal kv-tile (global index)
  const float qs = 0.08838834764831845f * 1.44269504088896f; // scale*log2(e)

  const char* Kg = (const char*)(Kb + (size_t)bh * S_ * D_);
  const char* Vg = (const char*)(Vt + (size_t)bh * D_ * S_);

  // staging source offsets (pre-swizzled; LDS dest linear p = wave*2048+i*1024+lane*16)
  uint32_t koff[2], voff[2];
  #pragma unroll
  for (int i = 0; i < 2; i++){
    int kr = wave*8 + i*4 + (lane >> 4);          // K row (256B rows)
    koff[i] = kr*256 + (((lane & 15) ^ (kr & 15)) << 4);
    int vr = wave*32 + i*16 + (lane >> 2);        // V row d (64B rows)
    voff[i] = vr*(S_*2) + (((lane & 3) ^ ((vr >> 1) & 3)) << 4);
  }

  auto stage = [&](int buf, int t){
    const char* kp = Kg + t*8192;    // 32 rows * 256 B
    const char* vp = Vg + t*64;      // 32 kv * 2 B
    char* kd = (char*)&Klds[buf][0] + wave*2048;
    char* vd = (char*)&Vlds[buf][0] + wave*2048;
    #pragma unroll
    for (int i = 0; i < 2; i++){
      gld16(kp + koff[i], kd + i*1024);
      gld16(vp + voff[i], vd + i*1024);
    }
  };

  // Q fragments, pre-scaled: lane holds Q[wq0+q32][ds*16 + hf*8 + j]
  uint4 qf[8];
  {
    const float* Qp = Q + ((size_t)bh * S_ + (wq0 + q32)) * D_ + hf*8;
    #pragma unroll
    for (int ds = 0; ds < 8; ds++){
      float4 a = *(const float4*)(Qp + ds*16);
      float4 b = *(const float4*)(Qp + ds*16 + 4);
      bf16x8 q8;
      q8[0] = (__bf16)(a.x*qs); q8[1] = (__bf16)(a.y*qs);
      q8[2] = (__bf16)(a.z*qs); q8[3] = (__bf16)(a.w*qs);
      q8[4] = (__bf16)(b.x*qs); q8[5] = (__bf16)(b.y*qs);
      q8[6] = (__bf16)(b.z*qs); q8[7] = (__bf16)(b.w*qs);
      qf[ds] = __builtin_bit_cast(uint4, q8);
    }
  }

  f32x16 o[4];
  #pragma unroll
  for (int db = 0; db < 4; db++) o[db] = (f32x16)(0.f);
  float m_run = -INFINITY, l_run = 0.f;

  stage(0, t0);
  __syncthreads();

  int cur = 0;
  for (int t = t0; t < tEnd; ++t){
    if (t + 1 < tEnd) stage(cur ^ 1, t + 1);   // prefetch; drains at end barrier

    if (t <= dtw){
      const bool diag = (t == dtw);
      const char* Kc = (const char*)&Klds[cur][0];
      const char* Vc = (const char*)&Vlds[cur][0];

      // ---- swapped QK^T: S^T = mfma(A=K, B=Q^T), 32x32x16
      f32x16 sa = (f32x16)(0.f);
      __builtin_amdgcn_s_setprio(1);
      #pragma unroll
      for (int ds = 0; ds < 8; ds++){
        int cb = (q32*256 + ds*32 + hf*16) ^ ((q32 & 15) << 4);
        bf16x8 kf = *(const bf16x8*)(Kc + cb);
        sa = __builtin_amdgcn_mfma_f32_32x32x16_bf16(
               kf, __builtin_bit_cast(bf16x8, qf[ds]), sa, 0, 0, 0);
      }
      __builtin_amdgcn_s_setprio(0);

      // ---- online softmax (log2 domain, defer-max); lane owns q-row q32;
      // its 16 regs cover kv = (r&3)+8*(r>>2)+4hf; partner lane^32 has the rest.
      float p[16];
      float pm = -INFINITY;
      const int q_abs = wq0 + q32;
      #pragma unroll
      for (int r = 0; r < 16; r++){
        float s = sa[r];
        if (diag){
          int kvl = t*32 + (r & 3) + 8*(r >> 2) + 4*hf;
          if (kvl > q_abs) s = -1e30f;
        }
        p[r] = s;
        pm = fmaxf(pm, s);
      }
      pm = fmaxf(pm, __shfl_xor(pm, 32));
      if (__any(pm > m_run + 11.5f)){
        float mn  = fmaxf(m_run, pm);
        float fac = exp2f(m_run - mn);
        float fv[16];
        #pragma unroll
        for (int r = 0; r < 16; r++) fv[r] = __shfl(fac, (r & 3) + 8*(r >> 2) + 4*hf);
        #pragma unroll
        for (int db = 0; db < 4; db++)
          #pragma unroll
          for (int r = 0; r < 16; r++) o[db][r] *= fv[r];
        l_run *= fac;
        m_run = mn;
      }
      float rs = 0.f;
      #pragma unroll
      for (int i = 0; i < 16; i++){ p[i] = exp2f(p[i] - m_run); rs += p[i]; }
      rs += __shfl_xor(rs, 32);
      l_run += rs;

      // ---- pack P to bf16 pairs: Wp[m][tt] = pk(kv = 8m+4hf+2tt, +1)
      uint32_t Wp[4][2];
      #pragma unroll
      for (int m = 0; m < 4; m++){
        #pragma unroll
        for (int tt = 0; tt < 2; tt++){
          float lo = p[4*m + 2*tt];
          float hi = p[4*m + 2*tt + 1];
          asm("v_cvt_pk_bf16_f32 %0, %1, %2" : "=v"(Wp[m][tt]) : "v"(lo), "v"(hi));
        }
      }

      // ---- PV: A = P (permlane32_swap redistribution), B = V from LDS
      __builtin_amdgcn_s_setprio(1);
      #pragma unroll
      for (int Ks = 0; Ks < 2; Ks++){
        uint32_t d0 = Wp[2*Ks][0], d2 = Wp[2*Ks + 1][0];
        asm volatile("v_permlane32_swap_b32 %0, %1" : "+v"(d0), "+v"(d2));
        uint32_t d1 = Wp[2*Ks][1], d3 = Wp[2*Ks + 1][1];
        asm volatile("v_permlane32_swap_b32 %0, %1" : "+v"(d1), "+v"(d3));
        uint4 pw = make_uint4(d0, d1, d2, d3);
        bf16x8 paf = __builtin_bit_cast(bf16x8, pw);
        #pragma unroll
        for (int db = 0; db < 4; db++){
          int row = db*32 + q32;
          int vb = (row*64 + Ks*32 + hf*16) ^ (((row >> 1) & 3) << 4);
          bf16x8 vf = *(const bf16x8*)(Vc + vb);
          o[db] = __builtin_amdgcn_mfma_f32_32x32x16_bf16(paf, vf, o[db], 0, 0, 0);
        }
      }
      __builtin_amdgcn_s_setprio(0);
    }

    __syncthreads();   // drains prefetch + publishes buf[cur^1]
    cur ^= 1;
  }

  // ---- epilogue
  if (nc == 1){
    float rl[16];
    #pragma unroll
    for (int r = 0; r < 16; r++)
      rl[r] = 1.f / __shfl(l_run, (r & 3) + 8*(r >> 2) + 4*hf);
    float* Op = Out + ((size_t)bh * S_ + wq0) * D_;
    #pragma unroll
    for (int db = 0; db < 4; db++){
      #pragma unroll
      for (int r = 0; r < 16; r++){
        int qrow = (r & 3) + 8*(r >> 2) + 4*hf;
        Op[(size_t)qrow*D_ + db*32 + q32] = o[db][r] * rl[r];
      }
    }
  } else {
    const int slot = bh*36 + OFFT[qb - 4] + c;
    unsigned short* Po = Opart + (size_t)slot * (128*128);
    float* Ml = MLpart + (size_t)slot * 256;
    #pragma unroll
    for (int db = 0; db < 4; db++){
      #pragma unroll
      for (int r = 0; r < 16; r++){
        int row = wave*32 + (r & 3) + 8*(r >> 2) + 4*hf;
        __bf16 bv = (__bf16)o[db][r];
        Po[row*128 + db*32 + q32] = __builtin_bit_cast(unsigned short, bv);
      }
    }
    if (hf == 0){
      Ml[(wave*32 + q32)*2 + 0] = m_run;
      Ml[(wave*32 + q32)*2 + 1] = l_run;
    }
  }
}

// ---------- combine kernel: merge the 2-4 kv-chunks of qb>=4 ----------
__global__ __launch_bounds__(256)
void combine(const unsigned short* __restrict__ Opart,
             const float* __restrict__ MLpart, float* __restrict__ Out){
  const int bx = blockIdx.x;            // 0..383 = bh*12 + (qb-4)
  const int bh = bx / 12, qi = bx % 12, qb = qi + 4;
  const int nc = (qb >> 2) + 1;
  const int base = bh*36 + OFFT[qi];
  const int row  = threadIdx.x >> 1;
  const int half = threadIdx.x & 1;

  float m[4] = {-INFINITY,-INFINITY,-INFINITY,-INFINITY};
  float l[4] = {0.f,0.f,0.f,0.f};
  float M = -INFINITY;
  #pragma unroll
  for (int c = 0; c < 4; c++) if (c < nc){
    m[c] = MLpart[(size_t)(base+c)*256 + row*2];
    l[c] = MLpart[(size_t)(base+c)*256 + row*2 + 1];
    M = fmaxf(M, m[c]);
  }
  float w[4] = {0.f,0.f,0.f,0.f};
  float den = 0.f;
  #pragma unroll
  for (int c = 0; c < 4; c++) if (c < nc){
    w[c] = exp2f(m[c] - M);
    den += l[c]*w[c];
  }
  float inv = 1.f / den;

  float* Or = Out + ((size_t)bh * S_ + qb*128 + row) * D_ + half*64;
  #pragma unroll
  for (int cc = 0; cc < 64; cc += 8){
    float acc[8] = {0,0,0,0,0,0,0,0};
    #pragma unroll
    for (int c = 0; c < 4; c++) if (c < nc){
      const unsigned short* Pr = Opart + (size_t)(base+c)*16384 + row*128 + half*64 + cc;
      ushort4 a0 = *(const ushort4*)(Pr), a1 = *(const ushort4*)(Pr + 4);
      acc[0] += bf2f(a0.x)*w[c]; acc[1] += bf2f(a0.y)*w[c];
      acc[2] += bf2f(a0.z)*w[c]; acc[3] += bf2f(a0.w)*w[c];
      acc[4] += bf2f(a1.x)*w[c]; acc[5] += bf2f(a1.y)*w[c];
      acc[6] += bf2f(a1.z)*w[c]; acc[7] += bf2f(a1.w)*w[c];
    }
    #pragma unroll
    for (int j = 0; j < 8; j++) Or[cc + j] = acc[j]*inv;
  }
}

extern "C" void kernel_launch(void* const* d_in, const int* in_sizes, int n_in,
                              void* d_out, int out_size, void* d_ws, size_t ws_size,
                              hipStream_t stream){
  const float* Q = (const float*)d_in[0];
  const float* K = (const float*)d_in[1];
  const float* V = (const float*)d_in[2];
  float* Out = (float*)d_out;

  unsigned short* Kb = (unsigned short*)d_ws;                  // 16.78 MB
  unsigned short* Vt = Kb + (size_t)BH_ * S_ * D_;             // 16.78 MB
  unsigned short* Opart = Vt + (size_t)BH_ * S_ * D_;          // 1152 x 32KB = 37.75 MB
  float* MLpart = (float*)(Opart + (size_t)1152 * 128 * 128);  // 1.18 MB

  const size_t need = (size_t)BH_*S_*D_*2*2
                    + (size_t)1152*128*128*2 + (size_t)1152*256*4;
  const int split = (ws_size >= need) ? 1 : 0;

  prep<<<dim3(S_/64, D_/64, BH_), 256, 0, stream>>>(K, V, Kb, Vt);
  attn_fwd<<<split ? 1280 : 512, 256, 0, stream>>>(Q, Kb, Vt, Out, Opart, MLpart, split);
  if (split) combine<<<384, 256, 0, stream>>>(Opart, MLpart, Out);
}